// Round 2
// baseline (223.655 us; speedup 1.0000x reference)
//
#include <hip/hip_runtime.h>

typedef __attribute__((ext_vector_type(8))) short bf16x8;
typedef __attribute__((ext_vector_type(4))) float f32x4;

#define MFMA_BF16 __builtin_amdgcn_mfma_f32_16x16x32_bf16

__device__ __forceinline__ unsigned short f2bf(float f) {
  union { float f; unsigned u; } v; v.f = f;
  unsigned r = v.u + 0x7FFFu + ((v.u >> 16) & 1u);
  return (unsigned short)(r >> 16);
}
__device__ __forceinline__ float sigm(float x) {
  return __builtin_amdgcn_rcpf(1.f + __expf(-x));
}
__device__ __forceinline__ float tanh_f(float x) {
  return 1.f - 2.f * __builtin_amdgcn_rcpf(1.f + __expf(2.f * x));
}

// ---------------------------------------------------------------------------
// K1: x = relu(layernorm(obs @ W0 + b0)) -> bf16 [131072, 64]
// 512 blocks x 512 thr (8 waves). Each block: stage W0 once, then 2 tiles of
// 128 rows (wave w -> 16 rows). W0 in LDS frag-major:
//   shorts[((kf*4+nt)*64 + lane)*8 + j] = W0[kf*32 + (lane>>4)*8 + j][nt*16 + (lane&15)]
// -> ds_read_b128 at lane*16 + imm (lane-linear, conflict-free, no addr VALU).
// ---------------------------------------------------------------------------
__global__ __launch_bounds__(512, 4) void k_dense_ln(
    const float* __restrict__ obs, const float* __restrict__ W0,
    const float* __restrict__ b0, const float* __restrict__ gam,
    const float* __restrict__ bet, unsigned short* __restrict__ xout) {
  __shared__ unsigned short wt[64 * 512];  // 64KB, frag-major
  const int tid = threadIdx.x;
  for (int q = tid; q < 4096; q += 512) {
    int f = q >> 6, l = q & 63;
    int k0 = (f >> 2) * 32 + ((l >> 4) << 3);
    int n = (f & 3) * 16 + (l & 15);
    bf16x8 v;
#pragma unroll
    for (int j = 0; j < 8; ++j) v[j] = (short)f2bf(W0[(k0 + j) * 64 + n]);
    *(bf16x8*)(wt + q * 8) = v;
  }
  __syncthreads();

  const int w = tid >> 6, l = tid & 63;
  const int g = l >> 4, c = l & 15;

  float b0v[4], gv[4], bv[4];
#pragma unroll
  for (int nt = 0; nt < 4; ++nt) {
    int col = nt * 16 + c;
    b0v[nt] = b0[col]; gv[nt] = gam[col]; bv[nt] = bet[col];
  }

  const unsigned short* wl = wt + l * 8;  // lane-linear base

  for (int it = 0; it < 2; ++it) {
    const long rb = ((long)blockIdx.x * 2 + it) * 128 + w * 16;
    f32x4 acc[4];
#pragma unroll
    for (int nt = 0; nt < 4; ++nt) acc[nt] = (f32x4){0.f, 0.f, 0.f, 0.f};

    const float* arow = obs + (rb + c) * 512 + g * 8;
    float4 a0 = *(const float4*)(arow);
    float4 a1 = *(const float4*)(arow + 4);
#pragma unroll
    for (int kf = 0; kf < 16; ++kf) {
      bf16x8 af;
      af[0] = (short)f2bf(a0.x); af[1] = (short)f2bf(a0.y);
      af[2] = (short)f2bf(a0.z); af[3] = (short)f2bf(a0.w);
      af[4] = (short)f2bf(a1.x); af[5] = (short)f2bf(a1.y);
      af[6] = (short)f2bf(a1.z); af[7] = (short)f2bf(a1.w);
      if (kf < 15) {  // prefetch next kf while MFMAs run
        a0 = *(const float4*)(arow + (kf + 1) * 32);
        a1 = *(const float4*)(arow + (kf + 1) * 32 + 4);
      }
#pragma unroll
      for (int nt = 0; nt < 4; ++nt) {
        bf16x8 bfr = *(const bf16x8*)(wl + (kf * 4 + nt) * 512);
        acc[nt] = MFMA_BF16(af, bfr, acc[nt], 0, 0, 0);
      }
    }

    // D layout: row = 4*g + r (in wave's 16-row tile), col = nt*16 + c
    float vv[4][4], s1[4], s2[4];
#pragma unroll
    for (int r = 0; r < 4; ++r) { s1[r] = 0.f; s2[r] = 0.f; }
#pragma unroll
    for (int nt = 0; nt < 4; ++nt)
#pragma unroll
      for (int r = 0; r < 4; ++r) {
        float val = acc[nt][r] + b0v[nt];
        vv[nt][r] = val; s1[r] += val; s2[r] += val * val;
      }
#pragma unroll
    for (int r = 0; r < 4; ++r) {
#pragma unroll
      for (int m = 1; m <= 8; m <<= 1) {
        s1[r] += __shfl_xor(s1[r], m);
        s2[r] += __shfl_xor(s2[r], m);
      }
    }
#pragma unroll
    for (int r = 0; r < 4; ++r) {
      float mu = s1[r] * 0.015625f;
      float var = s2[r] * 0.015625f - mu * mu;
      float inv = rsqrtf(var + 1e-12f);
      long row = rb + 4 * g + r;
#pragma unroll
      for (int nt = 0; nt < 4; ++nt) {
        float xn = (vv[nt][r] - mu) * inv * gv[nt] + bv[nt];
        xn = fmaxf(xn, 0.f);
        xout[row * 64 + nt * 16 + c] = f2bf(xn);
      }
    }
  }
}

// ---------------------------------------------------------------------------
// K2: bidirectional LSTM + fused output projection.
// 512 blocks x 256 thr: blk<256 -> fw, else bw; 16 sequences/block, 32 steps.
// x LDS frag-major (fidx = te*2+khalf, lane XOR fidx&7): reads lane-linear.
// h double-buffered frag-major -> ONE barrier per step (WAR gone).
// ---------------------------------------------------------------------------
__global__ __launch_bounds__(256, 2) void k_lstm(
    const unsigned short* __restrict__ x, const float* __restrict__ Wfw,
    const float* __restrict__ bfw, const float* __restrict__ Wbw,
    const float* __restrict__ bbw, const float* __restrict__ Wc,
    const float* __restrict__ bc, float* __restrict__ out) {
  __shared__ unsigned short xl[64 * 64 * 8];  // 64 frags * 64 lanes * 8 = 64KB
  __shared__ unsigned short hl[2 * 2 * 64 * 8];  // 2 bufs * 2 frags * 1KB
  const int tid = threadIdx.x, w = tid >> 6, l = tid & 63;
  const int g = l >> 4, c = l & 15;
  const int dir = blockIdx.x >> 8;
  const int sq = (blockIdx.x & 255) * 16;
  const float* W = dir ? Wbw : Wfw;
  const float* bias = dir ? bbw : bfw;

  // B fragments in registers: col = gate*64 + w*16 + c, k = kf*32 + g*8 + j
  bf16x8 Bf[4][4];
#pragma unroll
  for (int gate = 0; gate < 4; ++gate) {
    const int col = gate * 64 + w * 16 + c;
#pragma unroll
    for (int kf = 0; kf < 4; ++kf)
#pragma unroll
      for (int j = 0; j < 8; ++j)
        Bf[gate][kf][j] = (short)f2bf(W[(kf * 32 + g * 8 + j) * 256 + col]);
  }
  float bz[4];
#pragma unroll
  for (int gate = 0; gate < 4; ++gate) bz[gate] = bias[gate * 64 + w * 16 + c];

  // projection B-frags (wave 0, cols >= 8 zero-padded)
  bf16x8 Pc[2];
#pragma unroll
  for (int kf = 0; kf < 2; ++kf)
#pragma unroll
    for (int j = 0; j < 8; ++j) Pc[kf][j] = 0;
  float bcv = 0.f;
  if (w == 0 && c < 8) {
#pragma unroll
    for (int kf = 0; kf < 2; ++kf)
#pragma unroll
      for (int j = 0; j < 8; ++j)
        Pc[kf][j] = (short)f2bf(Wc[(kf * 32 + g * 8 + j) * 8 + c]);
    bcv = bc[c];
  }

  // stage x tile frag-major: chunk q: s=q>>8, te=(q>>3)&31, u0=q&7
  // -> frag fidx = te*2 + (u0>>2), dst lane = ((u0&3)*16 + s) ^ (fidx&7)
  const unsigned short* xg = x + (long)sq * 2048;
  for (int q = tid; q < 4096; q += 256) {
    bf16x8 v = *(const bf16x8*)(xg + q * 8);
    int s = q >> 8, te = (q >> 3) & 31, u0 = q & 7;
    int fidx = te * 2 + (u0 >> 2);
    int dl = ((u0 & 3) * 16 + s) ^ (fidx & 7);
    *(bf16x8*)(xl + (fidx * 64 + dl) * 8) = v;
  }
  for (int i = tid; i < 512; i += 256) ((unsigned*)hl)[i] = 0u;  // zero buf 0
  float cs[4] = {0.f, 0.f, 0.f, 0.f};
  __syncthreads();

  // h write slots: u = w*16+c -> q = w>>1, dlane = ((w&1)*2 + (c>>3))*16 + s
  const int hq = w >> 1;
  const int hgp = ((w & 1) * 2 + (c >> 3)) * 16;
  const int hlo = c & 7;

  int p = 0;
  for (int t = 0; t < 32; ++t) {
    const int te = dir ? 31 - t : t;
    const int f0 = te * 2, f1 = te * 2 + 1;
    bf16x8 Ax0 = *(const bf16x8*)(xl + (f0 * 64 + (l ^ (f0 & 7))) * 8);
    bf16x8 Ax1 = *(const bf16x8*)(xl + (f1 * 64 + (l ^ (f1 & 7))) * 8);
    bf16x8 Ah0 = *(const bf16x8*)(hl + p * 1024 + l * 8);
    bf16x8 Ah1 = *(const bf16x8*)(hl + p * 1024 + (64 + l) * 8);

    f32x4 acc[4];
#pragma unroll
    for (int gate = 0; gate < 4; ++gate)
      acc[gate] = (f32x4){bz[gate], bz[gate], bz[gate], bz[gate]};
#pragma unroll
    for (int gate = 0; gate < 4; ++gate) {
      acc[gate] = MFMA_BF16(Ax0, Bf[gate][0], acc[gate], 0, 0, 0);
      acc[gate] = MFMA_BF16(Ax1, Bf[gate][1], acc[gate], 0, 0, 0);
      acc[gate] = MFMA_BF16(Ah0, Bf[gate][2], acc[gate], 0, 0, 0);
      acc[gate] = MFMA_BF16(Ah1, Bf[gate][3], acc[gate], 0, 0, 0);
    }

    // i,j,f,o ; cell s = 4g+r, unit u = w*16+c
    const int wb = (p ^ 1) * 1024;
#pragma unroll
    for (int r = 0; r < 4; ++r) {
      float si = sigm(acc[0][r]);
      float tj = tanh_f(acc[1][r]);
      float sf = sigm(acc[2][r] + 1.f);
      float so = sigm(acc[3][r]);
      cs[r] = cs[r] * sf + si * tj;
      hl[wb + (hq * 64 + hgp + 4 * g + r) * 8 + hlo] = f2bf(tanh_f(cs[r]) * so);
    }
    __syncthreads();  // h(t) visible; reads of h(t-1) were from other buffer

    if (w == 0) {
      bf16x8 Ph0 = *(const bf16x8*)(hl + wb + l * 8);
      bf16x8 Ph1 = *(const bf16x8*)(hl + wb + (64 + l) * 8);
      f32x4 pa = (f32x4){0.f, 0.f, 0.f, 0.f};
      pa = MFMA_BF16(Ph0, Pc[0], pa, 0, 0, 0);
      pa = MFMA_BF16(Ph1, Pc[1], pa, 0, 0, 0);
      if (c < 8) {
#pragma unroll
        for (int r = 0; r < 4; ++r) {
          long orow = (long)dir * 4096 + sq + 4 * g + r;
          out[(orow * 32 + te) * 8 + c] = tanh_f(pa[r] + bcv);
        }
      }
    }
    p ^= 1;
  }
}

extern "C" void kernel_launch(void* const* d_in, const int* in_sizes, int n_in,
                              void* d_out, int out_size, void* d_ws, size_t ws_size,
                              hipStream_t stream) {
  const float* obs = (const float*)d_in[0];
  const float* W0  = (const float*)d_in[1];
  const float* b0  = (const float*)d_in[2];
  const float* gam = (const float*)d_in[3];
  const float* bet = (const float*)d_in[4];
  const float* Wfw = (const float*)d_in[5];
  const float* bfw = (const float*)d_in[6];
  const float* Wbw = (const float*)d_in[7];
  const float* bbw = (const float*)d_in[8];
  const float* Wc  = (const float*)d_in[9];
  const float* bc  = (const float*)d_in[10];
  float* out = (float*)d_out;
  unsigned short* xbf = (unsigned short*)d_ws;  // 131072*64 bf16 = 16.8 MB

  k_dense_ln<<<512, 512, 0, stream>>>(obs, W0, b0, gam, bet, xbf);
  k_lstm<<<512, 256, 0, stream>>>(xbf, Wfw, bfw, Wbw, bbw, Wc, bc, out);
}

// Round 3
// 111.737 us; speedup vs baseline: 2.0016x; 2.0016x over previous
//
#include <hip/hip_runtime.h>

typedef __attribute__((ext_vector_type(8))) short bf16x8;
typedef __attribute__((ext_vector_type(4))) float f32x4;

#define MFMA_BF16 __builtin_amdgcn_mfma_f32_16x16x32_bf16

__device__ __forceinline__ unsigned short f2bf(float f) {
  union { float f; unsigned u; } v; v.f = f;
  unsigned r = v.u + 0x7FFFu + ((v.u >> 16) & 1u);
  return (unsigned short)(r >> 16);
}
__device__ __forceinline__ float sigm(float x) {
  return __builtin_amdgcn_rcpf(1.f + __expf(-x));
}
__device__ __forceinline__ float tanh_f(float x) {
  return 1.f - 2.f * __builtin_amdgcn_rcpf(1.f + __expf(2.f * x));
}

// ---------------------------------------------------------------------------
// k0: one-time weight conversion to frag-major bf16 tables in d_ws.
// wfrag  (64 KB): W0 frags, f = kf*4+nt, lane l: W0[kf*32+(l>>4)*8+j][nt*16+(l&15)]
// wlstm (128 KB): per dir, f = w*16+gate*4+kf, lane l:
//                 W[(kf*32+(l>>4)*8+j)*256 + gate*64+w*16+(l&15)]
// ---------------------------------------------------------------------------
__global__ void k0_conv(const float* __restrict__ W0, const float* __restrict__ Wfw,
                        const float* __restrict__ Wbw, unsigned short* __restrict__ wfrag,
                        unsigned short* __restrict__ wlstm) {
  int gid = blockIdx.x * 256 + threadIdx.x;
  if (gid < 4096) {
    int f = gid >> 6, l = gid & 63;
    int k0 = (f >> 2) * 32 + ((l >> 4) << 3);
    int n = (f & 3) * 16 + (l & 15);
    bf16x8 v;
#pragma unroll
    for (int j = 0; j < 8; ++j) v[j] = (short)f2bf(W0[(k0 + j) * 64 + n]);
    *(bf16x8*)(wfrag + gid * 8) = v;
  } else if (gid < 12288) {
    int g2 = gid - 4096;
    const float* W = (g2 < 4096) ? Wfw : Wbw;
    int f = (g2 & 4095) >> 6, l = g2 & 63;
    int wv = f >> 4, gate = (f >> 2) & 3, kf = f & 3;
    int col = gate * 64 + wv * 16 + (l & 15);
    int kr = kf * 32 + ((l >> 4) << 3);
    bf16x8 v;
#pragma unroll
    for (int j = 0; j < 8; ++j) v[j] = (short)f2bf(W[(kr + j) * 256 + col]);
    *(bf16x8*)(wlstm + g2 * 8) = v;
  }
}

// ---------------------------------------------------------------------------
// K1: x = relu(layernorm(obs @ W0 + b0)) -> bf16 [131072, 64]
// 2048 blocks x 256 thr; wave -> 16 rows. B-frags straight from L2-resident
// wfrag (no big LDS -> VGPR-limited occupancy). Double-buffered obs + B loads.
// Store path: per-wave 2KB LDS transpose -> 2x global_store_dwordx4 / thread.
// ---------------------------------------------------------------------------
__global__ __launch_bounds__(256, 2) void k_dense_ln(
    const float* __restrict__ obs, const unsigned short* __restrict__ wfrag,
    const float* __restrict__ b0, const float* __restrict__ gam,
    const float* __restrict__ bet, unsigned short* __restrict__ xout) {
  __shared__ unsigned short xs[4096];  // 4 waves * 2KB
  const int tid = threadIdx.x, w = tid >> 6, l = tid & 63;
  const int g = l >> 4, c = l & 15;
  const long rb = (long)blockIdx.x * 64 + w * 16;

  float b0v[4], gv[4], bv[4];
#pragma unroll
  for (int nt = 0; nt < 4; ++nt) {
    int col = nt * 16 + c;
    b0v[nt] = b0[col]; gv[nt] = gam[col]; bv[nt] = bet[col];
  }

  const float* arow = obs + (rb + c) * 512 + g * 8;  // A row m = c
  const unsigned short* wfl = wfrag + l * 8;

  f32x4 acc[4];
#pragma unroll
  for (int nt = 0; nt < 4; ++nt) acc[nt] = (f32x4){0.f, 0.f, 0.f, 0.f};

  float4 a0 = *(const float4*)(arow);
  float4 a1 = *(const float4*)(arow + 4);
  bf16x8 Bc[4];
#pragma unroll
  for (int nt = 0; nt < 4; ++nt) Bc[nt] = *(const bf16x8*)(wfl + nt * 512);

#pragma unroll
  for (int kf = 0; kf < 16; ++kf) {
    bf16x8 af;
    af[0] = (short)f2bf(a0.x); af[1] = (short)f2bf(a0.y);
    af[2] = (short)f2bf(a0.z); af[3] = (short)f2bf(a0.w);
    af[4] = (short)f2bf(a1.x); af[5] = (short)f2bf(a1.y);
    af[6] = (short)f2bf(a1.z); af[7] = (short)f2bf(a1.w);
    float4 n0, n1;
    bf16x8 Bn[4];
    if (kf < 15) {  // depth-1 double buffer: issue next-iter loads first
      n0 = *(const float4*)(arow + (kf + 1) * 32);
      n1 = *(const float4*)(arow + (kf + 1) * 32 + 4);
#pragma unroll
      for (int nt = 0; nt < 4; ++nt)
        Bn[nt] = *(const bf16x8*)(wfl + ((kf + 1) * 4 + nt) * 512);
    }
#pragma unroll
    for (int nt = 0; nt < 4; ++nt)
      acc[nt] = MFMA_BF16(af, Bc[nt], acc[nt], 0, 0, 0);
    if (kf < 15) {
      a0 = n0; a1 = n1;
#pragma unroll
      for (int nt = 0; nt < 4; ++nt) Bc[nt] = Bn[nt];
    }
  }

  // D layout: row = 4*g + r (within wave's 16-row tile), col = nt*16 + c
  float vv[4][4], s1[4], s2[4];
#pragma unroll
  for (int r = 0; r < 4; ++r) { s1[r] = 0.f; s2[r] = 0.f; }
#pragma unroll
  for (int nt = 0; nt < 4; ++nt)
#pragma unroll
    for (int r = 0; r < 4; ++r) {
      float val = acc[nt][r] + b0v[nt];
      vv[nt][r] = val; s1[r] += val; s2[r] += val * val;
    }
#pragma unroll
  for (int r = 0; r < 4; ++r) {
#pragma unroll
    for (int m = 1; m <= 8; m <<= 1) {
      s1[r] += __shfl_xor(s1[r], m);
      s2[r] += __shfl_xor(s2[r], m);
    }
  }
  unsigned short* xw = xs + w * 1024;
#pragma unroll
  for (int r = 0; r < 4; ++r) {
    float mu = s1[r] * 0.015625f;
    float var = s2[r] * 0.015625f - mu * mu;
    float inv = rsqrtf(var + 1e-12f);
    int row = g * 4 + r;
#pragma unroll
    for (int nt = 0; nt < 4; ++nt) {
      float xn = (vv[nt][r] - mu) * inv * gv[nt] + bv[nt];
      xw[(row * 64 + nt * 16 + c) ^ (g << 3)] = f2bf(fmaxf(xn, 0.f));
    }
  }
  // within-wave transpose: lgkmcnt inserted by compiler, no barrier needed
#pragma unroll
  for (int m2 = 0; m2 < 2; ++m2) {
    int m = m2 * 64 + l;
    int row = m >> 3, u8 = m & 7;
    bf16x8 v = *(const bf16x8*)(xw + ((row * 64 + u8 * 8) ^ ((row >> 2) << 3)));
    *(bf16x8*)(xout + (rb + row) * 64 + u8 * 8) = v;
  }
}

// ---------------------------------------------------------------------------
// K2: bidirectional LSTM + fused output projection (structure unchanged from
// the passing R1 version; only the weight preamble now reads frag-major bf16).
// ---------------------------------------------------------------------------
__global__ __launch_bounds__(256, 2) void k_lstm(
    const unsigned short* __restrict__ x, const unsigned short* __restrict__ wlstm,
    const float* __restrict__ bfw, const float* __restrict__ bbw,
    const float* __restrict__ Wc, const float* __restrict__ bc,
    float* __restrict__ out) {
  __shared__ unsigned short xl[64 * 64 * 8];     // 64KB frag-major x tile
  __shared__ unsigned short hl[2 * 2 * 64 * 8];  // double-buffered h
  const int tid = threadIdx.x, w = tid >> 6, l = tid & 63;
  const int g = l >> 4, c = l & 15;
  const int dir = blockIdx.x >> 8;
  const int sq = (blockIdx.x & 255) * 16;
  const float* bias = dir ? bbw : bfw;

  bf16x8 Bf[4][4];
  const unsigned short* wl = wlstm + ((long)dir * 4096 + w * 16 * 64) * 8;
#pragma unroll
  for (int gate = 0; gate < 4; ++gate)
#pragma unroll
    for (int kf = 0; kf < 4; ++kf)
      Bf[gate][kf] = *(const bf16x8*)(wl + ((gate * 4 + kf) * 64 + l) * 8);
  float bz[4];
#pragma unroll
  for (int gate = 0; gate < 4; ++gate) bz[gate] = bias[gate * 64 + w * 16 + c];

  bf16x8 Pc[2];
#pragma unroll
  for (int kf = 0; kf < 2; ++kf)
#pragma unroll
    for (int j = 0; j < 8; ++j) Pc[kf][j] = 0;
  float bcv = 0.f;
  if (w == 0 && c < 8) {
#pragma unroll
    for (int kf = 0; kf < 2; ++kf)
#pragma unroll
      for (int j = 0; j < 8; ++j)
        Pc[kf][j] = (short)f2bf(Wc[(kf * 32 + g * 8 + j) * 8 + c]);
    bcv = bc[c];
  }

  const unsigned short* xg = x + (long)sq * 2048;
  for (int q = tid; q < 4096; q += 256) {
    bf16x8 v = *(const bf16x8*)(xg + q * 8);
    int s = q >> 8, te = (q >> 3) & 31, u0 = q & 7;
    int fidx = te * 2 + (u0 >> 2);
    int dl = ((u0 & 3) * 16 + s) ^ (fidx & 7);
    *(bf16x8*)(xl + (fidx * 64 + dl) * 8) = v;
  }
  for (int i = tid; i < 512; i += 256) ((unsigned*)hl)[i] = 0u;
  float cs[4] = {0.f, 0.f, 0.f, 0.f};
  __syncthreads();

  const int hq = w >> 1;
  const int hgp = ((w & 1) * 2 + (c >> 3)) * 16;
  const int hlo = c & 7;

  int p = 0;
  for (int t = 0; t < 32; ++t) {
    const int te = dir ? 31 - t : t;
    const int f0 = te * 2, f1 = te * 2 + 1;
    bf16x8 Ax0 = *(const bf16x8*)(xl + (f0 * 64 + (l ^ (f0 & 7))) * 8);
    bf16x8 Ax1 = *(const bf16x8*)(xl + (f1 * 64 + (l ^ (f1 & 7))) * 8);
    bf16x8 Ah0 = *(const bf16x8*)(hl + p * 1024 + l * 8);
    bf16x8 Ah1 = *(const bf16x8*)(hl + p * 1024 + (64 + l) * 8);

    f32x4 acc[4];
#pragma unroll
    for (int gate = 0; gate < 4; ++gate)
      acc[gate] = (f32x4){bz[gate], bz[gate], bz[gate], bz[gate]};
#pragma unroll
    for (int gate = 0; gate < 4; ++gate) {
      acc[gate] = MFMA_BF16(Ax0, Bf[gate][0], acc[gate], 0, 0, 0);
      acc[gate] = MFMA_BF16(Ax1, Bf[gate][1], acc[gate], 0, 0, 0);
      acc[gate] = MFMA_BF16(Ah0, Bf[gate][2], acc[gate], 0, 0, 0);
      acc[gate] = MFMA_BF16(Ah1, Bf[gate][3], acc[gate], 0, 0, 0);
    }

    const int wb = (p ^ 1) * 1024;
#pragma unroll
    for (int r = 0; r < 4; ++r) {
      float si = sigm(acc[0][r]);
      float tj = tanh_f(acc[1][r]);
      float sf = sigm(acc[2][r] + 1.f);
      float so = sigm(acc[3][r]);
      cs[r] = cs[r] * sf + si * tj;
      hl[wb + (hq * 64 + hgp + 4 * g + r) * 8 + hlo] = f2bf(tanh_f(cs[r]) * so);
    }
    __syncthreads();

    if (w == 0) {
      bf16x8 Ph0 = *(const bf16x8*)(hl + wb + l * 8);
      bf16x8 Ph1 = *(const bf16x8*)(hl + wb + (64 + l) * 8);
      f32x4 pa = (f32x4){0.f, 0.f, 0.f, 0.f};
      pa = MFMA_BF16(Ph0, Pc[0], pa, 0, 0, 0);
      pa = MFMA_BF16(Ph1, Pc[1], pa, 0, 0, 0);
      if (c < 8) {
#pragma unroll
        for (int r = 0; r < 4; ++r) {
          long orow = (long)dir * 4096 + sq + 4 * g + r;
          out[(orow * 32 + te) * 8 + c] = tanh_f(pa[r] + bcv);
        }
      }
    }
    p ^= 1;
  }
}

extern "C" void kernel_launch(void* const* d_in, const int* in_sizes, int n_in,
                              void* d_out, int out_size, void* d_ws, size_t ws_size,
                              hipStream_t stream) {
  const float* obs = (const float*)d_in[0];
  const float* W0  = (const float*)d_in[1];
  const float* b0  = (const float*)d_in[2];
  const float* gam = (const float*)d_in[3];
  const float* bet = (const float*)d_in[4];
  const float* Wfw = (const float*)d_in[5];
  const float* bfw = (const float*)d_in[6];
  const float* Wbw = (const float*)d_in[7];
  const float* bbw = (const float*)d_in[8];
  const float* Wc  = (const float*)d_in[9];
  const float* bc  = (const float*)d_in[10];
  float* out = (float*)d_out;

  unsigned short* wfrag = (unsigned short*)d_ws;       // 64 KB
  unsigned short* wlstm = wfrag + 4096 * 8;            // 128 KB
  unsigned short* xbf   = wlstm + 8192 * 8;            // 16.78 MB

  k0_conv<<<48, 256, 0, stream>>>(W0, Wfw, Wbw, wfrag, wlstm);
  k_dense_ln<<<2048, 256, 0, stream>>>(obs, wfrag, b0, gam, bet, xbf);
  k_lstm<<<512, 256, 0, stream>>>(xbf, wlstm, bfw, bbw, Wc, bc, out);
}

// Round 4
// 106.024 us; speedup vs baseline: 2.1095x; 1.0539x over previous
//
#include <hip/hip_runtime.h>
#include <hip/hip_bf16.h>

typedef __attribute__((ext_vector_type(8))) short bf16x8;
typedef __attribute__((ext_vector_type(4))) float f32x4;

#define MFMA_BF16 __builtin_amdgcn_mfma_f32_16x16x32_bf16

__device__ __forceinline__ unsigned pk2(float a, float b) {
  __hip_bfloat162 t = __float22bfloat162_rn(make_float2(a, b));
  return *reinterpret_cast<unsigned*>(&t);
}
__device__ __forceinline__ unsigned short f2bf_hw(float f) {
  __hip_bfloat16 h = __float2bfloat16(f);
  return *reinterpret_cast<unsigned short*>(&h);
}
__device__ __forceinline__ float sigm(float x) {
  return __builtin_amdgcn_rcpf(1.f + __expf(-x));
}
__device__ __forceinline__ float tanh_f(float x) {
  return 1.f - 2.f * __builtin_amdgcn_rcpf(1.f + __expf(2.f * x));
}

// ---------------------------------------------------------------------------
// k0: one-time weight conversion to frag-major bf16 tables in d_ws.
// ---------------------------------------------------------------------------
__global__ void k0_conv(const float* __restrict__ W0, const float* __restrict__ Wfw,
                        const float* __restrict__ Wbw, unsigned short* __restrict__ wfrag,
                        unsigned short* __restrict__ wlstm) {
  int gid = blockIdx.x * 256 + threadIdx.x;
  if (gid < 4096) {
    int f = gid >> 6, l = gid & 63;
    int k0 = (f >> 2) * 32 + ((l >> 4) << 3);
    int n = (f & 3) * 16 + (l & 15);
    bf16x8 v;
#pragma unroll
    for (int j = 0; j < 8; ++j) v[j] = (short)f2bf_hw(W0[(k0 + j) * 64 + n]);
    *(bf16x8*)(wfrag + gid * 8) = v;
  } else if (gid < 12288) {
    int g2 = gid - 4096;
    const float* W = (g2 < 4096) ? Wfw : Wbw;
    int f = (g2 & 4095) >> 6, l = g2 & 63;
    int wv = f >> 4, gate = (f >> 2) & 3, kf = f & 3;
    int col = gate * 64 + wv * 16 + (l & 15);
    int kr = kf * 32 + ((l >> 4) << 3);
    bf16x8 v;
#pragma unroll
    for (int j = 0; j < 8; ++j) v[j] = (short)f2bf_hw(W[(kr + j) * 256 + col]);
    *(bf16x8*)(wlstm + g2 * 8) = v;
  }
}

// ---------------------------------------------------------------------------
// K1: x = relu(layernorm(obs @ W0 + b0)) -> bf16 [131072, 64]
// Structure unchanged from R3 (passing); conversions now HW v_cvt_pk.
// ---------------------------------------------------------------------------
__global__ __launch_bounds__(256, 2) void k_dense_ln(
    const float* __restrict__ obs, const unsigned short* __restrict__ wfrag,
    const float* __restrict__ b0, const float* __restrict__ gam,
    const float* __restrict__ bet, unsigned short* __restrict__ xout) {
  __shared__ unsigned short xs[4096];  // 4 waves * 2KB
  const int tid = threadIdx.x, w = tid >> 6, l = tid & 63;
  const int g = l >> 4, c = l & 15;
  const long rb = (long)blockIdx.x * 64 + w * 16;

  float b0v[4], gv[4], bv[4];
#pragma unroll
  for (int nt = 0; nt < 4; ++nt) {
    int col = nt * 16 + c;
    b0v[nt] = b0[col]; gv[nt] = gam[col]; bv[nt] = bet[col];
  }

  const float* arow = obs + (rb + c) * 512 + g * 8;  // A row m = c
  const unsigned short* wfl = wfrag + l * 8;

  f32x4 acc[4];
#pragma unroll
  for (int nt = 0; nt < 4; ++nt) acc[nt] = (f32x4){0.f, 0.f, 0.f, 0.f};

  float4 a0 = *(const float4*)(arow);
  float4 a1 = *(const float4*)(arow + 4);
  bf16x8 Bc[4];
#pragma unroll
  for (int nt = 0; nt < 4; ++nt) Bc[nt] = *(const bf16x8*)(wfl + nt * 512);

#pragma unroll
  for (int kf = 0; kf < 16; ++kf) {
    union { bf16x8 v; unsigned u[4]; } af;
    af.u[0] = pk2(a0.x, a0.y); af.u[1] = pk2(a0.z, a0.w);
    af.u[2] = pk2(a1.x, a1.y); af.u[3] = pk2(a1.z, a1.w);
    float4 n0, n1;
    bf16x8 Bn[4];
    if (kf < 15) {  // depth-1 double buffer
      n0 = *(const float4*)(arow + (kf + 1) * 32);
      n1 = *(const float4*)(arow + (kf + 1) * 32 + 4);
#pragma unroll
      for (int nt = 0; nt < 4; ++nt)
        Bn[nt] = *(const bf16x8*)(wfl + ((kf + 1) * 4 + nt) * 512);
    }
#pragma unroll
    for (int nt = 0; nt < 4; ++nt)
      acc[nt] = MFMA_BF16(af.v, Bc[nt], acc[nt], 0, 0, 0);
    if (kf < 15) {
      a0 = n0; a1 = n1;
#pragma unroll
      for (int nt = 0; nt < 4; ++nt) Bc[nt] = Bn[nt];
    }
  }

  float vv[4][4], s1[4], s2[4];
#pragma unroll
  for (int r = 0; r < 4; ++r) { s1[r] = 0.f; s2[r] = 0.f; }
#pragma unroll
  for (int nt = 0; nt < 4; ++nt)
#pragma unroll
    for (int r = 0; r < 4; ++r) {
      float val = acc[nt][r] + b0v[nt];
      vv[nt][r] = val; s1[r] += val; s2[r] += val * val;
    }
#pragma unroll
  for (int r = 0; r < 4; ++r) {
#pragma unroll
    for (int m = 1; m <= 8; m <<= 1) {
      s1[r] += __shfl_xor(s1[r], m);
      s2[r] += __shfl_xor(s2[r], m);
    }
  }
  unsigned short* xw = xs + w * 1024;
#pragma unroll
  for (int r = 0; r < 4; ++r) {
    float mu = s1[r] * 0.015625f;
    float var = s2[r] * 0.015625f - mu * mu;
    float inv = rsqrtf(var + 1e-12f);
    int row = g * 4 + r;
#pragma unroll
    for (int nt = 0; nt < 4; ++nt) {
      float xn = (vv[nt][r] - mu) * inv * gv[nt] + bv[nt];
      xw[(row * 64 + nt * 16 + c) ^ (g << 3)] = f2bf_hw(fmaxf(xn, 0.f));
    }
  }
#pragma unroll
  for (int m2 = 0; m2 < 2; ++m2) {
    int m = m2 * 64 + l;
    int row = m >> 3, u8 = m & 7;
    bf16x8 v = *(const bf16x8*)(xw + ((row * 64 + u8 * 8) ^ ((row >> 2) << 3)));
    *(bf16x8*)(xout + (rb + row) * 64 + u8 * 8) = v;
  }
}

// ---------------------------------------------------------------------------
// K2: bidirectional LSTM + fused projection. 512 blocks x 256 thr.
// x streamed per-step through a 4-slot LDS ring (2KB/slot); h double-buffered.
// LDS total 12KB. Projection of h(t-1) by wave0 AFTER the barrier, reusing
// the Ah register frags (no extra LDS reads); post-loop handles h(31).
// ---------------------------------------------------------------------------
__global__ __launch_bounds__(256, 2) void k_lstm(
    const unsigned short* __restrict__ x, const unsigned short* __restrict__ wlstm,
    const float* __restrict__ bfw, const float* __restrict__ bbw,
    const float* __restrict__ Wc, const float* __restrict__ bc,
    float* __restrict__ out) {
  __shared__ unsigned short xr[4 * 1024];  // 4 slots * 2 frags * 64 lanes * 8
  __shared__ unsigned short hl[2 * 1024];  // 2 bufs * 2 frags * 64 lanes * 8
  const int tid = threadIdx.x, w = tid >> 6, l = tid & 63;
  const int g = l >> 4, c = l & 15;
  const int dir = blockIdx.x >> 8;
  const int sq = (blockIdx.x & 255) * 16;
  const float* bias = dir ? bbw : bfw;

  bf16x8 Bf[4][4];
  const unsigned short* wl = wlstm + ((long)dir * 4096 + w * 16 * 64) * 8;
#pragma unroll
  for (int gate = 0; gate < 4; ++gate)
#pragma unroll
    for (int kf = 0; kf < 4; ++kf)
      Bf[gate][kf] = *(const bf16x8*)(wl + ((gate * 4 + kf) * 64 + l) * 8);
  float bz[4];
#pragma unroll
  for (int gate = 0; gate < 4; ++gate) bz[gate] = bias[gate * 64 + w * 16 + c];

  bf16x8 Pc[2];
#pragma unroll
  for (int kf = 0; kf < 2; ++kf)
#pragma unroll
    for (int j = 0; j < 8; ++j) Pc[kf][j] = 0;
  float bcv = 0.f;
  if (w == 0 && c < 8) {
#pragma unroll
    for (int kf = 0; kf < 2; ++kf)
#pragma unroll
      for (int j = 0; j < 8; ++j)
        Pc[kf][j] = (short)f2bf_hw(Wc[(kf * 32 + g * 8 + j) * 8 + c]);
    bcv = bc[c];
  }

  // x staging geometry: thread tid -> sRow = tid>>4, uc = tid&15 (8B = 4 units)
  const int sRow = tid >> 4, uc = tid & 15;
  const unsigned short* xg = x + ((long)(sq + sRow) * 32) * 64 + uc * 4;
  const unsigned xdst = ((unsigned)(((uc >> 3) * 64 + ((uc >> 1) & 3) * 16 + sRow) * 16 +
                                    (uc & 1) * 8));

  // prologue: stage slots 0 and 1
  {
    int te0 = dir ? 31 : 0, te1 = dir ? 30 : 1;
    uint2 v0 = *(const uint2*)(xg + te0 * 64);
    uint2 v1 = *(const uint2*)(xg + te1 * 64);
    *(uint2*)((char*)xr + 0 * 2048 + xdst) = v0;
    *(uint2*)((char*)xr + 1 * 2048 + xdst) = v1;
  }
  for (int i = tid; i < 512; i += 256) ((unsigned*)hl)[i] = 0u;  // zero h buf 0
  float cs[4] = {0.f, 0.f, 0.f, 0.f};
  __syncthreads();

  const int hq = w >> 1;
  const int hgp = ((w & 1) * 2 + (c >> 3)) * 16;
  const int hlo = c & 7;

  int p = 0;
  for (int t = 0; t < 32; ++t) {
    const int te = dir ? 31 - t : t;
    // issue prefetch for t+2 early (L3 latency hides under the step)
    uint2 pf;
    const bool do_pf = (t + 2 < 32);
    if (do_pf) {
      int tep = dir ? 29 - t : t + 2;
      pf = *(const uint2*)(xg + tep * 64);
    }

    const char* xs = (const char*)xr + (t & 3) * 2048;
    bf16x8 Ax0 = *(const bf16x8*)(xs + l * 16);
    bf16x8 Ax1 = *(const bf16x8*)(xs + 1024 + l * 16);
    bf16x8 Ah0 = *(const bf16x8*)((const char*)hl + p * 2048 + l * 16);
    bf16x8 Ah1 = *(const bf16x8*)((const char*)hl + p * 2048 + 1024 + l * 16);

    f32x4 acc[4];
#pragma unroll
    for (int gate = 0; gate < 4; ++gate)
      acc[gate] = (f32x4){bz[gate], bz[gate], bz[gate], bz[gate]};
#pragma unroll
    for (int gate = 0; gate < 4; ++gate) {
      acc[gate] = MFMA_BF16(Ax0, Bf[gate][0], acc[gate], 0, 0, 0);
      acc[gate] = MFMA_BF16(Ax1, Bf[gate][1], acc[gate], 0, 0, 0);
      acc[gate] = MFMA_BF16(Ah0, Bf[gate][2], acc[gate], 0, 0, 0);
      acc[gate] = MFMA_BF16(Ah1, Bf[gate][3], acc[gate], 0, 0, 0);
    }

    const int wb = (p ^ 1) * 1024;  // shorts offset of write buffer
#pragma unroll
    for (int r = 0; r < 4; ++r) {
      float si = sigm(acc[0][r]);
      float tj = tanh_f(acc[1][r]);
      float sf = sigm(acc[2][r] + 1.f);
      float so = sigm(acc[3][r]);
      cs[r] = cs[r] * sf + si * tj;
      hl[wb + (hq * 64 + hgp + 4 * g + r) * 8 + hlo] = f2bf_hw(tanh_f(cs[r]) * so);
    }
    if (do_pf) *(uint2*)((char*)xr + ((t + 2) & 3) * 2048 + xdst) = pf;
    __syncthreads();

    // projection of h(t-1) using this step's Ah frags (after barrier: waves
    // 1-3 proceed into step t+1 while wave0 does this)
    if (w == 0 && t >= 1) {
      f32x4 pa = (f32x4){0.f, 0.f, 0.f, 0.f};
      pa = MFMA_BF16(Ah0, Pc[0], pa, 0, 0, 0);
      pa = MFMA_BF16(Ah1, Pc[1], pa, 0, 0, 0);
      if (c < 8) {
        int tp = dir ? 32 - t : t - 1;
#pragma unroll
        for (int r = 0; r < 4; ++r) {
          long orow = (long)dir * 4096 + sq + 4 * g + r;
          out[(orow * 32 + tp) * 8 + c] = tanh_f(pa[r] + bcv);
        }
      }
    }
    p ^= 1;
  }

  // final projection: h(31) sits in hl[p]
  if (w == 0) {
    bf16x8 Ph0 = *(const bf16x8*)((const char*)hl + p * 2048 + l * 16);
    bf16x8 Ph1 = *(const bf16x8*)((const char*)hl + p * 2048 + 1024 + l * 16);
    f32x4 pa = (f32x4){0.f, 0.f, 0.f, 0.f};
    pa = MFMA_BF16(Ph0, Pc[0], pa, 0, 0, 0);
    pa = MFMA_BF16(Ph1, Pc[1], pa, 0, 0, 0);
    if (c < 8) {
      int tp = dir ? 0 : 31;
#pragma unroll
      for (int r = 0; r < 4; ++r) {
        long orow = (long)dir * 4096 + sq + 4 * g + r;
        out[(orow * 32 + tp) * 8 + c] = tanh_f(pa[r] + bcv);
      }
    }
  }
}

extern "C" void kernel_launch(void* const* d_in, const int* in_sizes, int n_in,
                              void* d_out, int out_size, void* d_ws, size_t ws_size,
                              hipStream_t stream) {
  const float* obs = (const float*)d_in[0];
  const float* W0  = (const float*)d_in[1];
  const float* b0  = (const float*)d_in[2];
  const float* gam = (const float*)d_in[3];
  const float* bet = (const float*)d_in[4];
  const float* Wfw = (const float*)d_in[5];
  const float* bfw = (const float*)d_in[6];
  const float* Wbw = (const float*)d_in[7];
  const float* bbw = (const float*)d_in[8];
  const float* Wc  = (const float*)d_in[9];
  const float* bc  = (const float*)d_in[10];
  float* out = (float*)d_out;

  unsigned short* wfrag = (unsigned short*)d_ws;       // 64 KB
  unsigned short* wlstm = wfrag + 4096 * 8;            // 128 KB
  unsigned short* xbf   = wlstm + 8192 * 8;            // 16.78 MB

  k0_conv<<<48, 256, 0, stream>>>(W0, Wfw, Wbw, wfrag, wlstm);
  k_dense_ln<<<2048, 256, 0, stream>>>(obs, wfrag, b0, gam, bet, xbf);
  k_lstm<<<512, 256, 0, stream>>>(xbf, wlstm, bfw, bbw, Wc, bc, out);
}

// Round 6
// 103.921 us; speedup vs baseline: 2.1522x; 1.0202x over previous
//
#include <hip/hip_runtime.h>
#include <hip/hip_bf16.h>

typedef __attribute__((ext_vector_type(8))) short bf16x8;
typedef __attribute__((ext_vector_type(4))) float f32x4;

#define MFMA_BF16 __builtin_amdgcn_mfma_f32_16x16x32_bf16

#define GLDS16(gp, lp)                                                        \
  __builtin_amdgcn_global_load_lds(                                           \
      (const __attribute__((address_space(1))) void*)(gp),                    \
      (__attribute__((address_space(3))) void*)(lp), 16, 0, 0)

__device__ __forceinline__ unsigned pk2(float a, float b) {
  __hip_bfloat162 t = __float22bfloat162_rn(make_float2(a, b));
  return *reinterpret_cast<unsigned*>(&t);
}
__device__ __forceinline__ unsigned short f2bf_hw(float f) {
  __hip_bfloat16 h = __float2bfloat16(f);
  return *reinterpret_cast<unsigned short*>(&h);
}
__device__ __forceinline__ float sigm(float x) {
  return __builtin_amdgcn_rcpf(1.f + __expf(-x));
}
__device__ __forceinline__ float tanh_f(float x) {
  return 1.f - 2.f * __builtin_amdgcn_rcpf(1.f + __expf(2.f * x));
}

// ---------------------------------------------------------------------------
// k0: one-time weight conversion to frag-major bf16 tables in d_ws.
// ---------------------------------------------------------------------------
__global__ void k0_conv(const float* __restrict__ W0, const float* __restrict__ Wfw,
                        const float* __restrict__ Wbw, unsigned short* __restrict__ wfrag,
                        unsigned short* __restrict__ wlstm) {
  int gid = blockIdx.x * 256 + threadIdx.x;
  if (gid < 4096) {
    int f = gid >> 6, l = gid & 63;
    int k0 = (f >> 2) * 32 + ((l >> 4) << 3);
    int n = (f & 3) * 16 + (l & 15);
    bf16x8 v;
#pragma unroll
    for (int j = 0; j < 8; ++j) v[j] = (short)f2bf_hw(W0[(k0 + j) * 64 + n]);
    *(bf16x8*)(wfrag + gid * 8) = v;
  } else if (gid < 12288) {
    int g2 = gid - 4096;
    const float* W = (g2 < 4096) ? Wfw : Wbw;
    int f = (g2 & 4095) >> 6, l = g2 & 63;
    int wv = f >> 4, gate = (f >> 2) & 3, kf = f & 3;
    int col = gate * 64 + wv * 16 + (l & 15);
    int kr = kf * 32 + ((l >> 4) << 3);
    bf16x8 v;
#pragma unroll
    for (int j = 0; j < 8; ++j) v[j] = (short)f2bf_hw(W[(kr + j) * 256 + col]);
    *(bf16x8*)(wlstm + g2 * 8) = v;
  }
}

// ---------------------------------------------------------------------------
// K1: x = relu(layernorm(obs @ W0 + b0)) -> bf16 [131072, 64]
// 2048 blocks x 256 thr. obs tile (64 rows x 512) staged in 4 chunks of 128
// floats via global_load_lds (contiguous 512B segments, pre-swizzled source),
// double-buffered 2x32KB, counted vmcnt + raw barriers. B-frags from L2 table.
// Wave w's A-rows are block-rows w*16 + c (R5 bug: forgot the w*16).
// ---------------------------------------------------------------------------
__global__ __launch_bounds__(256, 2) void k_dense_ln(
    const float* __restrict__ obs, const unsigned short* __restrict__ wfrag,
    const float* __restrict__ b0, const float* __restrict__ gam,
    const float* __restrict__ bet, unsigned short* __restrict__ xout) {
  __shared__ __align__(16) char lds[65536];
  const int tid = threadIdx.x, w = tid >> 6, l = tid & 63;
  const int g = l >> 4, c = l & 15;
  const long blk64 = (long)blockIdx.x * 64;
  const long rb = blk64 + w * 16;

  float b0v[4], gv[4], bv[4];
#pragma unroll
  for (int nt = 0; nt < 4; ++nt) {
    int col = nt * 16 + c;
    b0v[nt] = b0[col]; gv[nt] = gam[col]; bv[nt] = bet[col];
  }
  const unsigned short* wfl = wfrag + l * 8;

  // staging lane constants: LDS unit o = w*512 + i*64 + l  (16B units)
  //   r = o>>5 = w*16 + i*2 + (l>>5), u = o&31 ; global chunk = u ^ (r&7)
  const int sr0 = w * 16 + (l >> 5);
  const int su = l & 31;
  const char* gB = (const char*)obs + blk64 * 2048;  // 2048 B per row

  // drain preamble loads so the vmcnt FIFO holds only staging traffic
  asm volatile("s_waitcnt vmcnt(0)" ::: "memory");

#define K1_STAGE(q)                                                           \
  {                                                                           \
    _Pragma("unroll") for (int i = 0; i < 8; ++i) {                           \
      int r_ = sr0 + 2 * i;                                                   \
      int chk_ = su ^ (r_ & 7);                                               \
      const char* gp_ = gB + (long)r_ * 2048 + (q) * 512 + chk_ * 16;         \
      char* lp_ = lds + ((q) & 1) * 32768 + (w * 512 + i * 64) * 16;          \
      GLDS16(gp_, lp_);                                                       \
    }                                                                         \
  }

  K1_STAGE(0);
  K1_STAGE(1);

  f32x4 acc[4];
#pragma unroll
  for (int nt = 0; nt < 4; ++nt) acc[nt] = (f32x4){0.f, 0.f, 0.f, 0.f};

#pragma unroll
  for (int q = 0; q < 4; ++q) {
    if (q < 3) asm volatile("s_waitcnt vmcnt(8)" ::: "memory");
    else       asm volatile("s_waitcnt vmcnt(0)" ::: "memory");
    __builtin_amdgcn_s_barrier();
    __builtin_amdgcn_sched_barrier(0);

    // FIX vs R5: wave w's A-row m=c lives at block-row w*16 + c
    const char* bufb = lds + (q & 1) * 32768 + (w * 16 + c) * 512;
#pragma unroll
    for (int kf2 = 0; kf2 < 4; ++kf2) {
      bf16x8 B0 = *(const bf16x8*)(wfl + ((q * 4 + kf2) * 4 + 0) * 512);
      bf16x8 B1 = *(const bf16x8*)(wfl + ((q * 4 + kf2) * 4 + 1) * 512);
      bf16x8 B2 = *(const bf16x8*)(wfl + ((q * 4 + kf2) * 4 + 2) * 512);
      bf16x8 B3 = *(const bf16x8*)(wfl + ((q * 4 + kf2) * 4 + 3) * 512);
      int v0 = kf2 * 8 + g * 2;
      float4 f0 = *(const float4*)(bufb + ((v0 + 0) ^ (c & 7)) * 16);
      float4 f1 = *(const float4*)(bufb + ((v0 + 1) ^ (c & 7)) * 16);
      union { bf16x8 v; unsigned u[4]; } af;
      af.u[0] = pk2(f0.x, f0.y); af.u[1] = pk2(f0.z, f0.w);
      af.u[2] = pk2(f1.x, f1.y); af.u[3] = pk2(f1.z, f1.w);
      acc[0] = MFMA_BF16(af.v, B0, acc[0], 0, 0, 0);
      acc[1] = MFMA_BF16(af.v, B1, acc[1], 0, 0, 0);
      acc[2] = MFMA_BF16(af.v, B2, acc[2], 0, 0, 0);
      acc[3] = MFMA_BF16(af.v, B3, acc[3], 0, 0, 0);
    }
    if (q < 2) {
      __builtin_amdgcn_s_barrier();   // all waves done reading buf[q&1]
      __builtin_amdgcn_sched_barrier(0);
      K1_STAGE(q + 2);
    }
  }

  // LN epilogue (D: row = 4*g + r within wave tile, col = nt*16 + c)
  float vv[4][4], s1[4], s2[4];
#pragma unroll
  for (int r = 0; r < 4; ++r) { s1[r] = 0.f; s2[r] = 0.f; }
#pragma unroll
  for (int nt = 0; nt < 4; ++nt)
#pragma unroll
    for (int r = 0; r < 4; ++r) {
      float val = acc[nt][r] + b0v[nt];
      vv[nt][r] = val; s1[r] += val; s2[r] += val * val;
    }
#pragma unroll
  for (int r = 0; r < 4; ++r) {
#pragma unroll
    for (int m = 1; m <= 8; m <<= 1) {
      s1[r] += __shfl_xor(s1[r], m);
      s2[r] += __shfl_xor(s2[r], m);
    }
  }
  // per-wave transpose region: reuse buf0 (last read at q=2; q=3 barrier
  // already passed for all waves)
  unsigned short* xw = (unsigned short*)lds + w * 1024;
#pragma unroll
  for (int r = 0; r < 4; ++r) {
    float mu = s1[r] * 0.015625f;
    float var = s2[r] * 0.015625f - mu * mu;
    float inv = rsqrtf(var + 1e-12f);
    int row = g * 4 + r;
#pragma unroll
    for (int nt = 0; nt < 4; ++nt) {
      float xn = (vv[nt][r] - mu) * inv * gv[nt] + bv[nt];
      xw[(row * 64 + nt * 16 + c) ^ (g << 3)] = f2bf_hw(fmaxf(xn, 0.f));
    }
  }
#pragma unroll
  for (int m2 = 0; m2 < 2; ++m2) {
    int m = m2 * 64 + l;
    int row = m >> 3, u8 = m & 7;
    bf16x8 v = *(const bf16x8*)(xw + ((row * 64 + u8 * 8) ^ ((row >> 2) << 3)));
    *(bf16x8*)(xout + (rb + row) * 64 + u8 * 8) = v;
  }
}

// ---------------------------------------------------------------------------
// K2: bidirectional LSTM + fused projection. 512 blocks x 256 thr.
// Whole x tile (64KB) staged via global_load_lds: wave w owns consumption
// tiles [w*8, w*8+8), issued in consumption order; per-step owner does a
// counted vmcnt before the (raw) barrier. No vmcnt(0) drains in the loop.
// ---------------------------------------------------------------------------
__global__ __launch_bounds__(256, 2) void k_lstm(
    const unsigned short* __restrict__ x, const unsigned short* __restrict__ wlstm,
    const float* __restrict__ bfw, const float* __restrict__ bbw,
    const float* __restrict__ Wc, const float* __restrict__ bc,
    float* __restrict__ out) {
  __shared__ __align__(16) char xl[65536];       // 32 tiles * 2KB (consumption idx)
  __shared__ unsigned short hl[2 * 1024];        // 2 bufs * 2 frags * 64 * 8
  const int tid = threadIdx.x, w = tid >> 6, l = tid & 63;
  const int g = l >> 4, c = l & 15;
  const int dir = blockIdx.x >> 8;
  const int sq = (blockIdx.x & 255) * 16;
  const float* bias = dir ? bbw : bfw;

  bf16x8 Bf[4][4];
  const unsigned short* wl = wlstm + ((long)dir * 4096 + w * 16 * 64) * 8;
#pragma unroll
  for (int gate = 0; gate < 4; ++gate)
#pragma unroll
    for (int kf = 0; kf < 4; ++kf)
      Bf[gate][kf] = *(const bf16x8*)(wl + ((gate * 4 + kf) * 64 + l) * 8);
  float bz[4];
#pragma unroll
  for (int gate = 0; gate < 4; ++gate) bz[gate] = bias[gate * 64 + w * 16 + c];

  bf16x8 Pc[2];
#pragma unroll
  for (int kf = 0; kf < 2; ++kf)
#pragma unroll
    for (int j = 0; j < 8; ++j) Pc[kf][j] = 0;
  float bcv = 0.f;
  if (w == 0 && c < 8) {
#pragma unroll
    for (int kf = 0; kf < 2; ++kf)
#pragma unroll
      for (int j = 0; j < 8; ++j)
        Pc[kf][j] = (short)f2bf_hw(Wc[(kf * 32 + g * 8 + j) * 8 + c]);
    bcv = bc[c];
  }

  // drain preamble so vmcnt FIFO holds only staging traffic
  asm volatile("s_waitcnt vmcnt(0)" ::: "memory");

  // stage: wave w issues tiles tt = w*8+j (j ascending = consumption order)
  const int ss = l >> 3, sc = l & 7;
#pragma unroll
  for (int j = 0; j < 8; ++j) {
    int tt = w * 8 + j;
    int te = dir ? 31 - tt : tt;
#pragma unroll
    for (int p = 0; p < 2; ++p) {
      int s = p * 8 + ss;
      const char* gp = (const char*)x +
          ((long)(sq + s) * 32 + te) * 128 + (long)(sc ^ (s & 7)) * 16;
      char* lp = xl + tt * 2048 + p * 1024;
      GLDS16(gp, lp);
    }
  }

  for (int i = tid; i < 1024; i += 256) ((unsigned*)hl)[i] = 0u;
  float cs[4] = {0.f, 0.f, 0.f, 0.f};

  // preamble barrier: wave 0 guarantees tile 0 present (first 2 of its 16)
  if (w == 0) asm volatile("s_waitcnt vmcnt(14)" ::: "memory");
  asm volatile("s_waitcnt lgkmcnt(0)" ::: "memory");
  __builtin_amdgcn_s_barrier();
  __builtin_amdgcn_sched_barrier(0);

  const int hq = w >> 1;
  const int hgp = ((w & 1) * 2 + (c >> 3)) * 16;
  const int hlo = c & 7;

  int p = 0;
#pragma unroll
  for (int t = 0; t < 32; ++t) {
    const int te = dir ? 31 - t : t;
    const char* xt = xl + t * 2048 + c * 128;
    bf16x8 Ax0 = *(const bf16x8*)(xt + (long)((g) ^ (c & 7)) * 16);
    bf16x8 Ax1 = *(const bf16x8*)(xt + (long)((4 + g) ^ (c & 7)) * 16);
    bf16x8 Ah0 = *(const bf16x8*)((const char*)hl + p * 2048 + l * 16);
    bf16x8 Ah1 = *(const bf16x8*)((const char*)hl + p * 2048 + 1024 + l * 16);

    f32x4 acc[4];
#pragma unroll
    for (int gate = 0; gate < 4; ++gate)
      acc[gate] = (f32x4){bz[gate], bz[gate], bz[gate], bz[gate]};
#pragma unroll
    for (int gate = 0; gate < 4; ++gate) {
      acc[gate] = MFMA_BF16(Ax0, Bf[gate][0], acc[gate], 0, 0, 0);
      acc[gate] = MFMA_BF16(Ax1, Bf[gate][1], acc[gate], 0, 0, 0);
      acc[gate] = MFMA_BF16(Ah0, Bf[gate][2], acc[gate], 0, 0, 0);
      acc[gate] = MFMA_BF16(Ah1, Bf[gate][3], acc[gate], 0, 0, 0);
    }

    const int wb = (p ^ 1) * 1024;  // shorts
#pragma unroll
    for (int r = 0; r < 4; ++r) {
      float si = sigm(acc[0][r]);
      float tj = tanh_f(acc[1][r]);
      float sf = sigm(acc[2][r] + 1.f);
      float so = sigm(acc[3][r]);
      cs[r] = cs[r] * sf + si * tj;
      hl[wb + (hq * 64 + hgp + 4 * g + r) * 8 + hlo] = f2bf_hw(tanh_f(cs[r]) * so);
    }

    // bottom barrier: owner of tile t+1 ensures its data has landed
    if (t + 1 < 32) {
      if (w == ((t + 1) >> 3))
        asm volatile("s_waitcnt vmcnt(%0)" :: "i"(14 - 2 * ((t + 1) & 7)) : "memory");
    }
    asm volatile("s_waitcnt lgkmcnt(0)" ::: "memory");
    __builtin_amdgcn_s_barrier();
    __builtin_amdgcn_sched_barrier(0);

    // projection of h(t-1) by wave0 (reuses Ah frags), off the critical chain
    if (w == 0 && t >= 1) {
      f32x4 pa = (f32x4){0.f, 0.f, 0.f, 0.f};
      pa = MFMA_BF16(Ah0, Pc[0], pa, 0, 0, 0);
      pa = MFMA_BF16(Ah1, Pc[1], pa, 0, 0, 0);
      if (c < 8) {
        int tp = dir ? 32 - t : t - 1;
#pragma unroll
        for (int r = 0; r < 4; ++r) {
          long orow = (long)dir * 4096 + sq + 4 * g + r;
          out[(orow * 32 + tp) * 8 + c] = tanh_f(pa[r] + bcv);
        }
      }
    }
    p ^= 1;
  }

  if (w == 0) {
    bf16x8 Ph0 = *(const bf16x8*)((const char*)hl + p * 2048 + l * 16);
    bf16x8 Ph1 = *(const bf16x8*)((const char*)hl + p * 2048 + 1024 + l * 16);
    f32x4 pa = (f32x4){0.f, 0.f, 0.f, 0.f};
    pa = MFMA_BF16(Ph0, Pc[0], pa, 0, 0, 0);
    pa = MFMA_BF16(Ph1, Pc[1], pa, 0, 0, 0);
    if (c < 8) {
      int tp = dir ? 0 : 31;
#pragma unroll
      for (int r = 0; r < 4; ++r) {
        long orow = (long)dir * 4096 + sq + 4 * g + r;
        out[(orow * 32 + tp) * 8 + c] = tanh_f(pa[r] + bcv);
      }
    }
  }
}

extern "C" void kernel_launch(void* const* d_in, const int* in_sizes, int n_in,
                              void* d_out, int out_size, void* d_ws, size_t ws_size,
                              hipStream_t stream) {
  const float* obs = (const float*)d_in[0];
  const float* W0  = (const float*)d_in[1];
  const float* b0  = (const float*)d_in[2];
  const float* gam = (const float*)d_in[3];
  const float* bet = (const float*)d_in[4];
  const float* Wfw = (const float*)d_in[5];
  const float* bfw = (const float*)d_in[6];
  const float* Wbw = (const float*)d_in[7];
  const float* bbw = (const float*)d_in[8];
  const float* Wc  = (const float*)d_in[9];
  const float* bc  = (const float*)d_in[10];
  float* out = (float*)d_out;

  unsigned short* wfrag = (unsigned short*)d_ws;       // 64 KB
  unsigned short* wlstm = wfrag + 4096 * 8;            // 128 KB
  unsigned short* xbf   = wlstm + 8192 * 8;            // 16.78 MB

  k0_conv<<<48, 256, 0, stream>>>(W0, Wfw, Wbw, wfrag, wlstm);
  k_dense_ln<<<2048, 256, 0, stream>>>(obs, wfrag, b0, gam, bet, xbf);
  k_lstm<<<512, 256, 0, stream>>>(xbf, wlstm, bfw, bbw, Wc, bc, out);
}